// Round 1
// baseline (3259.167 us; speedup 1.0000x reference)
//
#include <hip/hip_runtime.h>
#include <stdint.h>

typedef uint16_t u16;
typedef unsigned long long u64;
typedef __attribute__((ext_vector_type(8))) short short8;   // 8 x bf16 bits (4 VGPRs)
typedef __attribute__((ext_vector_type(4))) float f32x4;

#define SCOPE __HIP_MEMORY_SCOPE_AGENT
#define FSTRIDE 16   // ints per edge flag line (64B)

static __device__ __forceinline__ float bf2f(u16 b) {
  union { uint32_t u; float f; } x; x.u = ((uint32_t)b) << 16; return x.f;
}
static __device__ __forceinline__ u16 f2bf(float f) {
  union { float f; uint32_t u; } x; x.f = f;
  uint32_t u = x.u;
  u += 0x7fffu + ((u >> 16) & 1u);   // RTNE
  return (u16)(u >> 16);
}
// inf-safe without clamps: exp(+inf)->inf, 1+inf=inf, rcp(inf)=0; exp(-inf)->0.
static __device__ __forceinline__ float sigm(float x) {
  return __builtin_amdgcn_rcpf(1.f + __expf(-x));
}
static __device__ __forceinline__ float tanhf_(float x) {
  return 1.f - 2.f * __builtin_amdgcn_rcpf(1.f + __expf(2.f * x));
}
// LDS-only barrier: does NOT drain vmcnt.
static __device__ __forceinline__ void lds_barrier() {
  asm volatile("s_waitcnt lgkmcnt(0)\n\ts_barrier" ::: "memory");
}
#define DRAIN0() asm volatile("s_waitcnt vmcnt(0)" ::: "memory")
#define DRAIN2() asm volatile("s_waitcnt vmcnt(2)" ::: "memory")
static __device__ __forceinline__ int imin(int a, int b) { return a < b ? a : b; }

// R10: step-granular pipelined handoff, zero fences, scratch-free.
// Diagnosis of R9 (2731us): MfmaUtil 3%, VALUBusy 12%, hbm 3.5% -> latency/sync
// bound, not BW bound. WRITE_SIZE excess ~260MB == pra[tt] dynamic-index scratch
// churn (rule #20). ACQUIRE/RELEASE agent fences emit L2 inv/wb per chunk per WG
// (the "~300GB/s wall" was fence-induced refetch). Fixes:
//  - records held in SCALAR regs (cra/crb -> nra/nrb), no arrays, no scratch.
//  - all atomics RELAXED; producer orders records-before-flag via counted
//    s_waitcnt vmcnt(2) (flag value deferred by 1 step so the drain never waits
//    on just-issued stores); per-wave flags fout[wid], consumer min4 -> no
//    __syncthreads anywhere in the steady loop (2 lds_barriers/step).
//  - next-step records primed during current step; probe loads double-buffered
//    across steps (issue at t, consume/publish at t+1) so poll latency is off
//    the critical path.
//  - encoder-phase ring lives in d_out (dead until pair31's first projection at
//    t=257; all encoder ring reads/writes complete before that in pipeline
//    order): R_e=16 slots of slack independent of workspace size. Decoder ring
//    in workspace (R_w as fits).
// MFMA 16x16x32 bf16 layouts (m89-verified):
//   A-frag: lane holds A[m=lane&15][k=(lane>>4)*8+j]
//   B-frag: lane holds B[k=(lane>>4)*8+j][n=lane&15]  (W row-major (N,K))
//   C/D: reg p -> (row=(lane>>4)*4+p, col=lane&15)
__global__ __launch_bounds__(256, 1) void gru_pipeline(
    const void* ctx_,
    const void* eWih0_, const void* eWih_, const void* eWhh_,
    const void* ebih_,  const void* ebhh_,
    const void* dWih0_, const void* dWih_, const void* dWhh_,
    const void* dbih_,  const void* dbhh_,
    const void* Wo_,    const void* bo_,   void* out_,
    int* __restrict__ pflag, int* __restrict__ cflag,
    u64* __restrict__ xbufW, int RW, int RE)
{
  const int tid  = threadIdx.x;
  const int lane = tid & 63;
  const int wid  = tid >> 6;
  const int rt   = wid >> 1;      // row-tile (16 batch rows each)
  const int cs   = wid & 1;       // gate-col half
  const int lo   = lane & 15;
  const int hi   = lane >> 4;
  const int blk  = blockIdx.x;
  const int P    = blk >> 2;      // layer pair 0..31  (layers 2P, 2P+1)
  const int g    = blk & 3;       // batch chunk
  const int LA   = 2 * P;
  const int LB   = 2 * P + 1;
  const int NKCA = (P == 0) ? 4 : 2;   // layer A k-chunks (K=128 for layer 0)
  const int RMW  = RW - 1;             // RW, RE are powers of two
  const int RME  = RE - 1;
  u64* xbufE = (u64*)out_;             // encoder-phase ring lives in d_out

  __shared__ __align__(16) u16 hbA[2][32 * 72];
  __shared__ __align__(16) u16 hbB[2][32 * 72];
  __shared__ __align__(16) u16 xstA[2][32 * 72];
  __shared__ __align__(16) u16 xstB[32 * 72];
  __shared__ int s_cnt, s_fin, s_cn;
  if (tid == 0) { s_cnt = 0; s_fin = 0; s_cn = 0; }
  for (int i = tid; i < 32 * 72; i += 256) {
    hbA[0][i] = 0; hbA[1][i] = 0; hbB[0][i] = 0; hbB[1][i] = 0;
    xstA[0][i] = 0; xstA[1][i] = 0; xstB[i] = 0;
  }
  __syncthreads();
  {  // dtype probe: even u16s of enc_bih
    u16 v = ((const u16*)ebih_)[2 * tid];
    int e = (v >> 7) & 0xFF;
    if (e >= 100 && e <= 126) atomicAdd(&s_cnt, 1);
  }
  __syncthreads();
  const bool bf = (s_cnt >= 128);   // true: bf16 tensors; false: fp32

  auto ld8 = [&](const void* p, int idx) -> short8 {
    if (bf) return *(const short8*)((const u16*)p + idx);
    const float* f = (const float*)p + idx;
    short8 r;
#pragma unroll
    for (int j = 0; j < 8; ++j) r[j] = (short)f2bf(f[j]);
    return r;
  };
  auto ld1 = [&](const void* p, int idx) -> float {
    return bf ? bf2f(((const u16*)p)[idx]) : ((const float*)p)[idx];
  };

  int T[6];
  T[0] = 2*cs; T[1] = 2*cs+1; T[2] = 4+2*cs; T[3] = 5+2*cs; T[4] = 8+2*cs; T[5] = 9+2*cs;

  short8 zf8 = {0,0,0,0,0,0,0,0};
  short8 whA[6][2], wiA[6][4];     // layer A (wiA[.][2..3] only for P==0)
  short8 whB[6][2], wiB[6][2];     // layer B
  short8 wo[2][2];                 // pair-31 only
  float  bov[2] = {0.f, 0.f};
  float brzA[4], binA[2], bhnA[2];
  float brzB[4], binB[2], bhnB[2];
#pragma unroll
  for (int a = 0; a < 6; ++a) {
    whA[a][0]=zf8; whA[a][1]=zf8; whB[a][0]=zf8; whB[a][1]=zf8;
    wiB[a][0]=zf8; wiB[a][1]=zf8;
#pragma unroll
    for (int b = 0; b < 4; ++b) wiA[a][b]=zf8;
  }
  wo[0][0]=wo[0][1]=wo[1][0]=wo[1][1]=zf8;

  auto load_phase = [&](int ph) {
    const void* WH = ph ? dWhh_ : eWhh_;
    const void* WIs = ph ? dWih_ : eWih_;
    const void* WI0 = ph ? dWih0_ : eWih0_;
    const void* bi = ph ? dbih_ : ebih_;
    const void* bh = ph ? dbhh_ : ebhh_;
    const void* WIA = (LA == 0) ? WI0 : WIs;
    const int  iA   = (LA == 0) ? 0 : (LA - 1) * 192 * 64;
    const int  KINA = (LA == 0) ? 128 : 64;
#pragma unroll
    for (int ti = 0; ti < 6; ++ti) {
#pragma unroll
      for (int kc = 0; kc < 2; ++kc) {
        whA[ti][kc] = ld8(WH, LA*192*64 + (T[ti]*16 + lo)*64 + kc*32 + hi*8);
        whB[ti][kc] = ld8(WH, LB*192*64 + (T[ti]*16 + lo)*64 + kc*32 + hi*8);
        wiB[ti][kc] = ld8(WIs, LA*192*64 + (T[ti]*16 + lo)*64 + kc*32 + hi*8); // Wih[LB-1]=Wih[LA]
      }
#pragma unroll
      for (int kc = 0; kc < 4; ++kc)
        if (kc < NKCA)
          wiA[ti][kc] = ld8(WIA, iA + (T[ti]*16 + lo)*KINA + kc*32 + hi*8);
    }
#pragma unroll
    for (int q = 0; q < 4; ++q) {
      brzA[q] = ld1(bi, LA*192 + T[q]*16 + lo) + ld1(bh, LA*192 + T[q]*16 + lo);
      brzB[q] = ld1(bi, LB*192 + T[q]*16 + lo) + ld1(bh, LB*192 + T[q]*16 + lo);
    }
#pragma unroll
    for (int q = 0; q < 2; ++q) {
      binA[q] = ld1(bi, LA*192 + T[4+q]*16 + lo);
      bhnA[q] = ld1(bh, LA*192 + T[4+q]*16 + lo);
      binB[q] = ld1(bi, LB*192 + T[4+q]*16 + lo);
      bhnB[q] = ld1(bh, LB*192 + T[4+q]*16 + lo);
    }
  };
  load_phase(0);
  if (P == 31) {
#pragma unroll
    for (int ct = 0; ct < 2; ++ct) {
      int n = 32*wid + 16*ct + lo;
#pragma unroll
      for (int kc = 0; kc < 2; ++kc)
        wo[ct][kc] = ld8(Wo_, n*64 + kc*32 + hi*8);
      bov[ct] = ld1(bo_, n);
    }
  }

  auto do_proj = [&](int tprev, const u16* hs) {
    f32x4 pacc[2][2];
#pragma unroll
    for (int rtl = 0; rtl < 2; ++rtl)
#pragma unroll
      for (int ct = 0; ct < 2; ++ct) {
        float v = bov[ct]; f32x4 tv = {v, v, v, v}; pacc[rtl][ct] = tv;
      }
#pragma unroll
    for (int kc = 0; kc < 2; ++kc) {
      short8 hA0 = *(const short8*)(hs + (0*16 + lo)*72 + kc*32 + hi*8);
      short8 hA1 = *(const short8*)(hs + (1*16 + lo)*72 + kc*32 + hi*8);
      pacc[0][0] = __builtin_amdgcn_mfma_f32_16x16x32_bf16(hA0, wo[0][kc], pacc[0][0], 0, 0, 0);
      pacc[0][1] = __builtin_amdgcn_mfma_f32_16x16x32_bf16(hA0, wo[1][kc], pacc[0][1], 0, 0, 0);
      pacc[1][0] = __builtin_amdgcn_mfma_f32_16x16x32_bf16(hA1, wo[0][kc], pacc[1][0], 0, 0, 0);
      pacc[1][1] = __builtin_amdgcn_mfma_f32_16x16x32_bf16(hA1, wo[1][kc], pacc[1][1], 0, 0, 0);
    }
#pragma unroll
    for (int rtl = 0; rtl < 2; ++rtl)
#pragma unroll
      for (int ct = 0; ct < 2; ++ct) {
        int n = 32*wid + 16*ct + lo;
#pragma unroll
        for (int p = 0; p < 4; ++p) {
          int b = 32*g + rtl*16 + hi*4 + p;
          size_t idx = ((size_t)b * 256 + (tprev - 256)) * 128 + n;
          float v = fminf(64.f, fmaxf(-64.f, pacc[rtl][ct][p]));
          if (bf) ((u16*)out_)[idx] = f2bf(v);
          else    ((float*)out_)[idx] = v;
        }
      }
  };

  float hprevA[2][4], hprevB[2][4];
#pragma unroll
  for (int q = 0; q < 2; ++q)
#pragma unroll
    for (int p = 0; p < 4; ++p) { hprevA[q][p] = 0.f; hprevB[q][p] = 0.f; }

  const int brow = 32*g + rt*16 + lo;

  const int eIn  = (P > 0 ? P - 1 : 0) * 4 + g;   // deref'd only when P>0
  const int eOut = (P < 31 ? P : 30) * 4 + g;     // deref'd only when P<31
  int* fin   = pflag + eIn  * FSTRIDE;            // 4 per-wave flags per edge
  int* fout  = pflag + eOut * FSTRIDE;
  int* cself = cflag + (P * 4 + g) * FSTRIDE;
  int* cnext = cflag + ((P < 31 ? P + 1 : 31) * 4 + g) * FSTRIDE;

  // ring slot for step t: encoder steps (t<256) in d_out, decoder in workspace.
  auto rin = [&](int t) -> const u64* {
    return (t < 256)
      ? (xbufE + (size_t)eIn * ((size_t)RE * 512) + (size_t)(t & RME) * 512)
      : (xbufW + (size_t)eIn * ((size_t)RW * 512) + (size_t)((t - 256) & RMW) * 512);
  };
  auto rout = [&](int t) -> u64* {
    return (t < 256)
      ? (xbufE + (size_t)eOut * ((size_t)RE * 512) + (size_t)(t & RME) * 512)
      : (xbufW + (size_t)eOut * ((size_t)RW * 512) + (size_t)((t - 256) & RMW) * 512);
  };

  int budget = 1 << 22;   // anti-hang
  const int srow = (tid >> 7) * 16 + ((tid >> 4) & 3) * 4;
  const int scol = ((tid >> 6) & 1) * 32 + (tid & 15);

  u64 cra = 0, crb = 0, nra = 0, nrb = 0;   // current / next step records (scalar!)
  int f0 = 0, f1 = 0, f2 = 0, f3 = 0, c0 = 0;  // tid0 probe holds (1-step delayed)

  __syncthreads();

  // ---- prologue: blocking wait + prime records(0)
  if (P > 0) {
    if (tid == 0) {
      int v = 0;
      while (budget > 0) {
        int a = __hip_atomic_load(fin + 0, __ATOMIC_RELAXED, SCOPE);
        int b = __hip_atomic_load(fin + 1, __ATOMIC_RELAXED, SCOPE);
        int c = __hip_atomic_load(fin + 2, __ATOMIC_RELAXED, SCOPE);
        int d = __hip_atomic_load(fin + 3, __ATOMIC_RELAXED, SCOPE);
        v = imin(imin(a, b), imin(c, d));
        if (v >= 1) break;
        --budget; __builtin_amdgcn_s_sleep(2);
      }
      s_fin = v;
    }
    __syncthreads();
    const u64* r0 = rin(0) + tid * 2;
    cra = __hip_atomic_load(r0,     __ATOMIC_RELAXED, SCOPE);
    crb = __hip_atomic_load(r0 + 1, __ATOMIC_RELAXED, SCOPE);
  }

#pragma unroll 1
  for (int t = 0; t < 512; ++t) {
    if (t == 256) load_phase(1);

    // uniform sync state (written pre-B2 of t-1 or pre-barrier of a slow path)
    int vfin = s_fin, vcn = s_cn;

    // ---- stage x_t for layer A -> xstA[t&1]
    if (P > 0) {
      u16* xd = xstA[t & 1];
#pragma unroll
      for (int p = 0; p < 4; ++p) {
        xd[(srow + p) * 72 + scol]      = (u16)(cra >> (16 * p));
        xd[(srow + p) * 72 + scol + 16] = (u16)(crb >> (16 * p));
      }
    }
    // fast-path prime of next step's records (overlaps with this step's compute)
    const bool prime_ok = (P > 0) && (t + 1 < 512) && (vfin >= t + 2);
    if (prime_ok) {
      const u64* rn = rin(t + 1) + tid * 2;
      nra = __hip_atomic_load(rn,     __ATOMIC_RELAXED, SCOPE);
      nrb = __hip_atomic_load(rn + 1, __ATOMIC_RELAXED, SCOPE);
    }

    lds_barrier();   // B1: xstA(t), hbA(t-1), hbB(t-1) visible

    // consumption credit: after B1 all waves have copied records(t) out of the ring
    if (P > 0 && tid == 0)
      __hip_atomic_store(cself, t + 1, __ATOMIC_RELAXED, SCOPE);

    // producer flow control for storing records(t) this step
    if (P < 31) {
      const int need = (t < 256) ? ((t >= RE) ? (t + 1 - RE) : 0)
                                 : ((t >= 256 + RW) ? (t + 1 - RW) : 0);
      if (need > 0 && vcn < need) {
        if (tid == 0) {
          int v = vcn;
          while (budget > 0) {
            v = __hip_atomic_load(cnext, __ATOMIC_RELAXED, SCOPE);
            if (v >= need) break;
            --budget; __builtin_amdgcn_s_sleep(2);
          }
          s_cn = v;
        }
        lds_barrier();
      }
    }

    // ---- pair 31: projection of step t-1 (h63_{t-1} in hbB[(t+1)&1])
    if (P == 31 && t >= 257) do_proj(t - 1, hbB[(t + 1) & 1]);

    // ================= layer A =================
    f32x4 acc_rz[4], acc_in[2], acc_hn[2];
#pragma unroll
    for (int q = 0; q < 4; ++q) { float v = brzA[q]; f32x4 tv = {v,v,v,v}; acc_rz[q] = tv; }
#pragma unroll
    for (int q = 0; q < 2; ++q) { float v = binA[q]; f32x4 tv = {v,v,v,v}; acc_in[q] = tv;
                                  float w = bhnA[q]; f32x4 tw = {w,w,w,w}; acc_hn[q] = tw; }
    const u16* hsA = hbA[(t + 1) & 1];
#pragma unroll
    for (int kc = 0; kc < 2; ++kc) {
      short8 hA = *(const short8*)(hsA + (rt*16 + lo)*72 + kc*32 + hi*8);
      acc_rz[0] = __builtin_amdgcn_mfma_f32_16x16x32_bf16(hA, whA[0][kc], acc_rz[0], 0, 0, 0);
      acc_rz[1] = __builtin_amdgcn_mfma_f32_16x16x32_bf16(hA, whA[1][kc], acc_rz[1], 0, 0, 0);
      acc_rz[2] = __builtin_amdgcn_mfma_f32_16x16x32_bf16(hA, whA[2][kc], acc_rz[2], 0, 0, 0);
      acc_rz[3] = __builtin_amdgcn_mfma_f32_16x16x32_bf16(hA, whA[3][kc], acc_rz[3], 0, 0, 0);
      acc_hn[0] = __builtin_amdgcn_mfma_f32_16x16x32_bf16(hA, whA[4][kc], acc_hn[0], 0, 0, 0);
      acc_hn[1] = __builtin_amdgcn_mfma_f32_16x16x32_bf16(hA, whA[5][kc], acc_hn[1], 0, 0, 0);
    }
    short8 xfA[4] = {zf8, zf8, zf8, zf8};
    if (P > 0) {
      const u16* xs = xstA[t & 1];
#pragma unroll
      for (int kc = 0; kc < 2; ++kc)
        xfA[kc] = *(const short8*)(xs + (rt*16 + lo)*72 + kc*32 + hi*8);
    } else {
      int tx = (t < 256) ? t : ((t == 256) ? 0 : t - 257);
#pragma unroll
      for (int kc = 0; kc < 4; ++kc)
        xfA[kc] = ld8(ctx_, (brow * 256 + tx) * 128 + kc*32 + hi*8);
    }
    if (!(P == 0 && t == 256)) {
#pragma unroll
      for (int kc = 0; kc < 4; ++kc) {
        if (kc < NKCA) {
          acc_rz[0] = __builtin_amdgcn_mfma_f32_16x16x32_bf16(xfA[kc], wiA[0][kc], acc_rz[0], 0, 0, 0);
          acc_rz[1] = __builtin_amdgcn_mfma_f32_16x16x32_bf16(xfA[kc], wiA[1][kc], acc_rz[1], 0, 0, 0);
          acc_rz[2] = __builtin_amdgcn_mfma_f32_16x16x32_bf16(xfA[kc], wiA[2][kc], acc_rz[2], 0, 0, 0);
          acc_rz[3] = __builtin_amdgcn_mfma_f32_16x16x32_bf16(xfA[kc], wiA[3][kc], acc_rz[3], 0, 0, 0);
          acc_in[0] = __builtin_amdgcn_mfma_f32_16x16x32_bf16(xfA[kc], wiA[4][kc], acc_in[0], 0, 0, 0);
          acc_in[1] = __builtin_amdgcn_mfma_f32_16x16x32_bf16(xfA[kc], wiA[5][kc], acc_in[1], 0, 0, 0);
        }
      }
    }
    u16 hAb[2][4];
#pragma unroll
    for (int q = 0; q < 2; ++q)
#pragma unroll
      for (int p = 0; p < 4; ++p) {
        float r = sigm(acc_rz[q][p]);
        float z = sigm(acc_rz[2 + q][p]);
        float n = tanhf_(acc_in[q][p] + r * acc_hn[q][p]);
        float h = n + z * (hprevA[q][p] - n);
        h = fminf(1.f, fmaxf(-1.f, h));
        hprevA[q][p] = h;
        hAb[q][p] = f2bf(h);
      }

    // probe publish (1-step-old values) + reissue; pre-B2 so readers at t+1 are ordered
    if (tid == 0) {
      if (P > 0)  s_fin = imin(imin(f0, f1), imin(f2, f3));
      if (P < 31) s_cn  = c0;
      if (P > 0) {
        f0 = __hip_atomic_load(fin + 0, __ATOMIC_RELAXED, SCOPE);
        f1 = __hip_atomic_load(fin + 1, __ATOMIC_RELAXED, SCOPE);
        f2 = __hip_atomic_load(fin + 2, __ATOMIC_RELAXED, SCOPE);
        f3 = __hip_atomic_load(fin + 3, __ATOMIC_RELAXED, SCOPE);
      }
      if (P < 31) c0 = __hip_atomic_load(cnext, __ATOMIC_RELAXED, SCOPE);
    }

    {  // h_A -> hbA[t&1] (recurrence) and xstB (x for layer B)
      u16* hd = hbA[t & 1];
#pragma unroll
      for (int q = 0; q < 2; ++q)
#pragma unroll
        for (int p = 0; p < 4; ++p) {
          int ridx = (rt*16 + hi*4 + p) * 72 + cs*32 + q*16 + lo;
          hd[ridx] = hAb[q][p];
          xstB[ridx] = hAb[q][p];
        }
    }

    lds_barrier();   // B2: xstB(t) visible

    // ================= layer B =================
#pragma unroll
    for (int q = 0; q < 4; ++q) { float v = brzB[q]; f32x4 tv = {v,v,v,v}; acc_rz[q] = tv; }
#pragma unroll
    for (int q = 0; q < 2; ++q) { float v = binB[q]; f32x4 tv = {v,v,v,v}; acc_in[q] = tv;
                                  float w = bhnB[q]; f32x4 tw = {w,w,w,w}; acc_hn[q] = tw; }
    const u16* hsB = hbB[(t + 1) & 1];
#pragma unroll
    for (int kc = 0; kc < 2; ++kc) {
      short8 hB = *(const short8*)(hsB + (rt*16 + lo)*72 + kc*32 + hi*8);
      short8 xB = *(const short8*)(xstB + (rt*16 + lo)*72 + kc*32 + hi*8);
      acc_rz[0] = __builtin_amdgcn_mfma_f32_16x16x32_bf16(hB, whB[0][kc], acc_rz[0], 0, 0, 0);
      acc_rz[1] = __builtin_amdgcn_mfma_f32_16x16x32_bf16(hB, whB[1][kc], acc_rz[1], 0, 0, 0);
      acc_rz[2] = __builtin_amdgcn_mfma_f32_16x16x32_bf16(hB, whB[2][kc], acc_rz[2], 0, 0, 0);
      acc_rz[3] = __builtin_amdgcn_mfma_f32_16x16x32_bf16(hB, whB[3][kc], acc_rz[3], 0, 0, 0);
      acc_hn[0] = __builtin_amdgcn_mfma_f32_16x16x32_bf16(hB, whB[4][kc], acc_hn[0], 0, 0, 0);
      acc_hn[1] = __builtin_amdgcn_mfma_f32_16x16x32_bf16(hB, whB[5][kc], acc_hn[1], 0, 0, 0);
      acc_rz[0] = __builtin_amdgcn_mfma_f32_16x16x32_bf16(xB, wiB[0][kc], acc_rz[0], 0, 0, 0);
      acc_rz[1] = __builtin_amdgcn_mfma_f32_16x16x32_bf16(xB, wiB[1][kc], acc_rz[1], 0, 0, 0);
      acc_rz[2] = __builtin_amdgcn_mfma_f32_16x16x32_bf16(xB, wiB[2][kc], acc_rz[2], 0, 0, 0);
      acc_rz[3] = __builtin_amdgcn_mfma_f32_16x16x32_bf16(xB, wiB[3][kc], acc_rz[3], 0, 0, 0);
      acc_in[0] = __builtin_amdgcn_mfma_f32_16x16x32_bf16(xB, wiB[4][kc], acc_in[0], 0, 0, 0);
      acc_in[1] = __builtin_amdgcn_mfma_f32_16x16x32_bf16(xB, wiB[5][kc], acc_in[1], 0, 0, 0);
    }
    u16 hBb[2][4];
#pragma unroll
    for (int q = 0; q < 2; ++q)
#pragma unroll
      for (int p = 0; p < 4; ++p) {
        float r = sigm(acc_rz[q][p]);
        float z = sigm(acc_rz[2 + q][p]);
        float n = tanhf_(acc_in[q][p] + r * acc_hn[q][p]);
        float h = n + z * (hprevB[q][p] - n);
        h = fminf(1.f, fmaxf(-1.f, h));
        hprevB[q][p] = h;
        hBb[q][p] = f2bf(h);
      }
    {
      u16* hd = hbB[t & 1];
#pragma unroll
      for (int q = 0; q < 2; ++q)
#pragma unroll
        for (int p = 0; p < 4; ++p)
          hd[(rt*16 + hi*4 + p) * 72 + cs*32 + q*16 + lo] = hBb[q][p];
    }
    if (P < 31) {   // record h_B for the next pair
      u64 da = (u64)hBb[0][0] | ((u64)hBb[0][1] << 16) | ((u64)hBb[0][2] << 32) | ((u64)hBb[0][3] << 48);
      u64 db = (u64)hBb[1][0] | ((u64)hBb[1][1] << 16) | ((u64)hBb[1][2] << 32) | ((u64)hBb[1][3] << 48);
      u64* ro = rout(t) + tid * 2;
      __hip_atomic_store(ro,     da, __ATOMIC_RELAXED, SCOPE);
      __hip_atomic_store(ro + 1, db, __ATOMIC_RELAXED, SCOPE);
    }

    // ---- flag release (per-wave; no __syncthreads anywhere in the loop)
    if (P < 31) {
      const bool df = ((t < 256) ? (RE >= 2) : (RW >= 2)) && (t < 511);
      if (df) {
        // vmcnt(2): everything except the 2 just-issued stores(t) is drained,
        // so records(<=t-1) are at the coherence point -> flag value t.
        DRAIN2();
        if (lane == 0) __hip_atomic_store(fout + wid, t, __ATOMIC_RELAXED, SCOPE);
      } else {
        DRAIN0();
        if (lane == 0) __hip_atomic_store(fout + wid, t + 1, __ATOMIC_RELAXED, SCOPE);
      }
    }

    // ---- slow data path: producer not far enough ahead; block + prime
    if (P > 0 && t + 1 < 512 && !prime_ok) {
      if (tid == 0) {
        int v = 0;
        while (budget > 0) {
          int a = __hip_atomic_load(fin + 0, __ATOMIC_RELAXED, SCOPE);
          int b = __hip_atomic_load(fin + 1, __ATOMIC_RELAXED, SCOPE);
          int c = __hip_atomic_load(fin + 2, __ATOMIC_RELAXED, SCOPE);
          int d = __hip_atomic_load(fin + 3, __ATOMIC_RELAXED, SCOPE);
          v = imin(imin(a, b), imin(c, d));
          if (v >= t + 2) break;
          --budget; __builtin_amdgcn_s_sleep(2);
        }
        s_fin = v;
      }
      lds_barrier();
      const u64* rn = rin(t + 1) + tid * 2;
      nra = __hip_atomic_load(rn,     __ATOMIC_RELAXED, SCOPE);
      nrb = __hip_atomic_load(rn + 1, __ATOMIC_RELAXED, SCOPE);
    }
    cra = nra; crb = nrb;
  }

  // ---- epilogue: final flag (covers deferred value) + last projection
  if (P < 31) {
    DRAIN0();
    if (lane == 0) __hip_atomic_store(fout + wid, 512, __ATOMIC_RELAXED, SCOPE);
  }
  lds_barrier();
  if (P == 31) do_proj(511, hbB[1]);
}

extern "C" void kernel_launch(void* const* d_in, const int* in_sizes, int n_in,
                              void* d_out, int out_size, void* d_ws, size_t ws_size,
                              hipStream_t stream)
{
  char* ws = (char*)d_ws;
  int* pflag = (int*)ws;                    // 124 edges x 64B per-wave flag lines
  int* cflag = (int*)(ws + 8192);           // 128 consumer-credit lines
  u64* xbufW = (u64*)(ws + 16384);          // decoder-phase handoff ring

  const size_t per_slot = (size_t)31 * 4 * 4096;  // one ring step across all 31x4 edges
  size_t avail = (ws_size > 16384) ? ws_size - 16384 : 0;
  int RW = 1;
  for (int r = 128; r >= 1; r >>= 1)
    if ((size_t)r * per_slot <= avail) { RW = r; break; }
  // encoder-phase ring borrows d_out (dead until pair31's first projection)
  int RE = 1;
  for (int r = 16; r >= 1; r >>= 1)
    if ((size_t)r * per_slot <= (size_t)out_size) { RE = r; break; }

  hipMemsetAsync(ws, 0, 16384, stream);     // zero flags every launch

  gru_pipeline<<<128, 256, 0, stream>>>(
      d_in[0], d_in[1], d_in[2], d_in[3], d_in[4], d_in[5],
      d_in[6], d_in[7], d_in[8], d_in[9], d_in[10], d_in[11], d_in[12],
      d_out, pflag, cflag, xbufW, RW, RE);
  (void)in_sizes; (void)n_in;
}

// Round 2
// 2343.764 us; speedup vs baseline: 1.3906x; 1.3906x over previous
//
#include <hip/hip_runtime.h>
#include <stdint.h>

typedef uint16_t u16;
typedef unsigned long long u64;
typedef __attribute__((ext_vector_type(8))) short short8;   // 8 x bf16 bits (4 VGPRs)
typedef __attribute__((ext_vector_type(4))) float f32x4;

#define SCOPE __HIP_MEMORY_SCOPE_AGENT
#define FSTRIDE 16   // ints per edge flag line (64B): 4 per-wave flags
#define FLD(p) __hip_atomic_load((p), __ATOMIC_RELAXED, SCOPE)
#define FST(p, v) __hip_atomic_store((p), (v), __ATOMIC_RELAXED, SCOPE)

template <int N> struct IC { static constexpr int value = N; };

static __device__ __forceinline__ float bf2f(u16 b) {
  union { uint32_t u; float f; } x; x.u = ((uint32_t)b) << 16; return x.f;
}
static __device__ __forceinline__ u16 f2bf(float f) {
  union { float f; uint32_t u; } x; x.f = f;
  uint32_t u = x.u;
  u += 0x7fffu + ((u >> 16) & 1u);   // RTNE
  return (u16)(u >> 16);
}
// inf-safe: exp(+inf)->inf, 1+inf=inf, rcp(inf)=0; exp(-inf)->0.
static __device__ __forceinline__ float sigm(float x) {
  return __builtin_amdgcn_rcpf(1.f + __expf(-x));
}
static __device__ __forceinline__ float tanhf_(float x) {
  return 1.f - 2.f * __builtin_amdgcn_rcpf(1.f + __expf(2.f * x));
}
// LDS-only barrier: does NOT drain vmcnt.
static __device__ __forceinline__ void lds_barrier() {
  asm volatile("s_waitcnt lgkmcnt(0)\n\ts_barrier" ::: "memory");
}
#define DRAIN0() asm volatile("s_waitcnt vmcnt(0)" ::: "memory")
static __device__ __forceinline__ int imin(int a, int b) { return a < b ? a : b; }

// R11: chunked (CH-step) relaxed-protocol pipeline, scratch-free, full-line ring.
// Post-mortem R10 (3259us, regression): per-STEP flags/drains/polls quadrupled
// sync cost vs R9's per-chunk protocol. WRITE_SIZE 563MB unchanged by scratch
// fix -> the 2.07x over the 260MB useful ring traffic is HALF-LINE stores
// (2 x dwordx2 at stride 16B per lane touch every 64B line twice). R9's residual
// wall: ACQUIRE/RELEASE emit per-chunk L2 inv/wb cache ops, serial chunk-start
// poll RTT, chunk-end __syncthreads convoy.
// R11 = R9 chunk skeleton + (1) fully-unrolled chunk body (static pa[]/pb[],
// rule #20), (2) RELAXED everywhere + per-wave DRAIN0->flag, consumer min4 (no
// cache maintenance, no syncthreads in loop), (3) probes issued 1 step early,
// published via LDS pre-B2 (poll RTT off critical path), (4) plane-split ring
// (full 64B lines both directions), (5) encoder ring in d_out (RE=16 slack
// guaranteed; dead until pair31's first proj at t=257), decoder ring in ws
// (CHD dispatched on RW).
// MFMA 16x16x32 bf16 layouts (m89-verified):
//   A-frag: lane holds A[m=lane&15][k=(lane>>4)*8+j]
//   B-frag: lane holds B[k=(lane>>4)*8+j][n=lane&15]  (W row-major (N,K))
//   C/D: reg p -> (row=(lane>>4)*4+p, col=lane&15)
template <int CHE, int CHD>
__global__ __launch_bounds__(256, 1) void gru_pipeline(
    const void* ctx_,
    const void* eWih0_, const void* eWih_, const void* eWhh_,
    const void* ebih_,  const void* ebhh_,
    const void* dWih0_, const void* dWih_, const void* dWhh_,
    const void* dbih_,  const void* dbhh_,
    const void* Wo_,    const void* bo_,   void* out_,
    int* __restrict__ pflag, int* __restrict__ cflag,
    u64* __restrict__ xbufW, int RW, int RE)
{
  const int tid  = threadIdx.x;
  const int lane = tid & 63;
  const int wid  = tid >> 6;
  const int rt   = wid >> 1;      // row-tile (16 batch rows each)
  const int cs   = wid & 1;       // gate-col half
  const int lo   = lane & 15;
  const int hi   = lane >> 4;
  const int blk  = blockIdx.x;
  const int P    = blk >> 2;      // layer pair 0..31  (layers 2P, 2P+1)
  const int g    = blk & 3;       // batch chunk
  const int LA   = 2 * P;
  const int LB   = 2 * P + 1;
  const int NKCA = (P == 0) ? 4 : 2;   // layer A k-chunks (K=128 for layer 0)
  u64* xbufE = (u64*)out_;             // encoder-phase ring lives in d_out

  __shared__ __align__(16) u16 hbA[2][32 * 72];
  __shared__ __align__(16) u16 hbB[2][32 * 72];
  __shared__ __align__(16) u16 xstA[2][32 * 72];
  __shared__ __align__(16) u16 xstB[32 * 72];
  __shared__ int s_cnt, s_fin, s_cn;
  if (tid == 0) { s_cnt = 0; s_fin = 0; s_cn = 0; }
  for (int i = tid; i < 32 * 72; i += 256) {
    hbA[0][i] = 0; hbA[1][i] = 0; hbB[0][i] = 0; hbB[1][i] = 0;
    xstA[0][i] = 0; xstA[1][i] = 0; xstB[i] = 0;
  }
  __syncthreads();
  {  // dtype probe: even u16s of enc_bih
    u16 v = ((const u16*)ebih_)[2 * tid];
    int e = (v >> 7) & 0xFF;
    if (e >= 100 && e <= 126) atomicAdd(&s_cnt, 1);
  }
  __syncthreads();
  const bool bf = (s_cnt >= 128);   // true: bf16 tensors; false: fp32

  auto ld8 = [&](const void* p, int idx) -> short8 {
    if (bf) return *(const short8*)((const u16*)p + idx);
    const float* f = (const float*)p + idx;
    short8 r;
#pragma unroll
    for (int j = 0; j < 8; ++j) r[j] = (short)f2bf(f[j]);
    return r;
  };
  auto ld1 = [&](const void* p, int idx) -> float {
    return bf ? bf2f(((const u16*)p)[idx]) : ((const float*)p)[idx];
  };

  int T[6];
  T[0] = 2*cs; T[1] = 2*cs+1; T[2] = 4+2*cs; T[3] = 5+2*cs; T[4] = 8+2*cs; T[5] = 9+2*cs;

  short8 zf8 = {0,0,0,0,0,0,0,0};
  short8 whA[6][2], wiA[6][4];     // layer A (wiA[.][2..3] only for P==0)
  short8 whB[6][2], wiB[6][2];     // layer B
  short8 wo[2][2];                 // pair-31 only
  float  bov[2] = {0.f, 0.f};
  float brzA[4], binA[2], bhnA[2];
  float brzB[4], binB[2], bhnB[2];
#pragma unroll
  for (int a = 0; a < 6; ++a) {
    whA[a][0]=zf8; whA[a][1]=zf8; whB[a][0]=zf8; whB[a][1]=zf8;
    wiB[a][0]=zf8; wiB[a][1]=zf8;
#pragma unroll
    for (int b = 0; b < 4; ++b) wiA[a][b]=zf8;
  }
  wo[0][0]=wo[0][1]=wo[1][0]=wo[1][1]=zf8;

  auto load_phase = [&](int ph) {
    const void* WH = ph ? dWhh_ : eWhh_;
    const void* WIs = ph ? dWih_ : eWih_;
    const void* WI0 = ph ? dWih0_ : eWih0_;
    const void* bi = ph ? dbih_ : ebih_;
    const void* bh = ph ? dbhh_ : ebhh_;
    const void* WIA = (LA == 0) ? WI0 : WIs;
    const int  iA   = (LA == 0) ? 0 : (LA - 1) * 192 * 64;
    const int  KINA = (LA == 0) ? 128 : 64;
#pragma unroll
    for (int ti = 0; ti < 6; ++ti) {
#pragma unroll
      for (int kc = 0; kc < 2; ++kc) {
        whA[ti][kc] = ld8(WH, LA*192*64 + (T[ti]*16 + lo)*64 + kc*32 + hi*8);
        whB[ti][kc] = ld8(WH, LB*192*64 + (T[ti]*16 + lo)*64 + kc*32 + hi*8);
        wiB[ti][kc] = ld8(WIs, LA*192*64 + (T[ti]*16 + lo)*64 + kc*32 + hi*8); // Wih[LB-1]=Wih[LA]
      }
#pragma unroll
      for (int kc = 0; kc < 4; ++kc)
        if (kc < NKCA)
          wiA[ti][kc] = ld8(WIA, iA + (T[ti]*16 + lo)*KINA + kc*32 + hi*8);
    }
#pragma unroll
    for (int q = 0; q < 4; ++q) {
      brzA[q] = ld1(bi, LA*192 + T[q]*16 + lo) + ld1(bh, LA*192 + T[q]*16 + lo);
      brzB[q] = ld1(bi, LB*192 + T[q]*16 + lo) + ld1(bh, LB*192 + T[q]*16 + lo);
    }
#pragma unroll
    for (int q = 0; q < 2; ++q) {
      binA[q] = ld1(bi, LA*192 + T[4+q]*16 + lo);
      bhnA[q] = ld1(bh, LA*192 + T[4+q]*16 + lo);
      binB[q] = ld1(bi, LB*192 + T[4+q]*16 + lo);
      bhnB[q] = ld1(bh, LB*192 + T[4+q]*16 + lo);
    }
  };
  load_phase(0);
  if (P == 31) {
#pragma unroll
    for (int ct = 0; ct < 2; ++ct) {
      int n = 32*wid + 16*ct + lo;
#pragma unroll
      for (int kc = 0; kc < 2; ++kc)
        wo[ct][kc] = ld8(Wo_, n*64 + kc*32 + hi*8);
      bov[ct] = ld1(bo_, n);
    }
  }

  auto do_proj = [&](int tprev, const u16* hs) {
    f32x4 pacc[2][2];
#pragma unroll
    for (int rtl = 0; rtl < 2; ++rtl)
#pragma unroll
      for (int ct = 0; ct < 2; ++ct) {
        float v = bov[ct]; f32x4 tv = {v, v, v, v}; pacc[rtl][ct] = tv;
      }
#pragma unroll
    for (int kc = 0; kc < 2; ++kc) {
      short8 hA0 = *(const short8*)(hs + (0*16 + lo)*72 + kc*32 + hi*8);
      short8 hA1 = *(const short8*)(hs + (1*16 + lo)*72 + kc*32 + hi*8);
      pacc[0][0] = __builtin_amdgcn_mfma_f32_16x16x32_bf16(hA0, wo[0][kc], pacc[0][0], 0, 0, 0);
      pacc[0][1] = __builtin_amdgcn_mfma_f32_16x16x32_bf16(hA0, wo[1][kc], pacc[0][1], 0, 0, 0);
      pacc[1][0] = __builtin_amdgcn_mfma_f32_16x16x32_bf16(hA1, wo[0][kc], pacc[1][0], 0, 0, 0);
      pacc[1][1] = __builtin_amdgcn_mfma_f32_16x16x32_bf16(hA1, wo[1][kc], pacc[1][1], 0, 0, 0);
    }
#pragma unroll
    for (int rtl = 0; rtl < 2; ++rtl)
#pragma unroll
      for (int ct = 0; ct < 2; ++ct) {
        int n = 32*wid + 16*ct + lo;
#pragma unroll
        for (int p = 0; p < 4; ++p) {
          int b = 32*g + rtl*16 + hi*4 + p;
          size_t idx = ((size_t)b * 256 + (tprev - 256)) * 128 + n;
          float v = fminf(64.f, fmaxf(-64.f, pacc[rtl][ct][p]));
          if (bf) ((u16*)out_)[idx] = f2bf(v);
          else    ((float*)out_)[idx] = v;
        }
      }
  };

  float hprevA[2][4], hprevB[2][4];
#pragma unroll
  for (int q = 0; q < 2; ++q)
#pragma unroll
    for (int p = 0; p < 4; ++p) { hprevA[q][p] = 0.f; hprevB[q][p] = 0.f; }

  const int brow = 32*g + rt*16 + lo;

  const int eIn  = (P > 0 ? P - 1 : 0) * 4 + g;   // deref'd only when P>0
  const int eOut = (P < 31 ? P : 30) * 4 + g;     // deref'd only when P<31
  int* fin   = pflag + eIn  * FSTRIDE;            // 4 per-wave producer flags
  int* fout  = pflag + eOut * FSTRIDE;
  int* cself = cflag + (P * 4 + g) * FSTRIDE;     // 4 per-wave consumer credits
  int* cnext = cflag + ((P < 31 ? P + 1 : 31) * 4 + g) * FSTRIDE;

  int budget = 1 << 22;   // anti-hang
  const int srow = (tid >> 7) * 16 + ((tid >> 4) & 3) * 4;
  const int scol = ((tid >> 6) & 1) * 32 + (tid & 15);

  int f0 = 0, f1 = 0, f2 = 0, f3 = 0;       // tid0 flag probes (issued 1 step early)
  int c0 = 0, c1 = 0, c2 = 0, c3 = 0;       // tid0 credit probes

  __syncthreads();

  // ---------------- chunked span: CH steps per chunk, fully unrolled ----------------
  auto span = [&](auto chc, const int tbase, const int cbase, const int RC, const bool dec) {
    constexpr int CH  = decltype(chc)::value;
    constexpr int PTT = (CH >= 2) ? CH - 2 : 0;   // probe-issue step
    const int NC   = 256 / CH;
    const int RM   = dec ? (RW - 1) : (RE - 1);
    const int toff = dec ? 256 : 0;
    const u64* rbi = dec ? (xbufW + (size_t)eIn  * ((size_t)RW * 512))
                         : (xbufE + (size_t)eIn  * ((size_t)RE * 512));
    u64*       rbo = dec ? (xbufW + (size_t)eOut * ((size_t)RW * 512))
                         : (xbufE + (size_t)eOut * ((size_t)RE * 512));

#pragma unroll 1
    for (int k = 0; k < NC; ++k) {
      const int ck    = cbase + k;
      const int t0    = tbase + k * CH;
      const int fneed = ck + 1;
      const int need  = (k >= RC) ? (cbase + k + 1 - RC) : 0;

      // ---- slow path only when pipelined probes say we're not ready (rare)
      const bool slowF = (P > 0)  && (s_fin < fneed);
      const bool slowC = (P < 31) && (need > 0) && (s_cn < need);
      if (slowF || slowC) {
        if (tid == 0) {
          if (slowF) {
            int v = 0;
            while (budget > 0) {
              int a = FLD(fin + 0), b = FLD(fin + 1), c = FLD(fin + 2), d = FLD(fin + 3);
              v = imin(imin(a, b), imin(c, d));
              if (v >= fneed) break;
              --budget; __builtin_amdgcn_s_sleep(2);
            }
            s_fin = v;
          }
          if (slowC) {
            int v = 0;
            while (budget > 0) {
              int a = FLD(cnext + 0), b = FLD(cnext + 1), c = FLD(cnext + 2), d = FLD(cnext + 3);
              v = imin(imin(a, b), imin(c, d));
              if (v >= need) break;
              --budget; __builtin_amdgcn_s_sleep(2);
            }
            s_cn = v;
          }
        }
        lds_barrier();
      }

      // ---- prime the whole chunk's records (static regs; plane-split full lines)
      u64 pa[CH], pb[CH];
#pragma unroll
      for (int j = 0; j < CH; ++j) { pa[j] = 0; pb[j] = 0; }
      if (P > 0) {
#pragma unroll
        for (int j = 0; j < CH; ++j) {
          const u64* rj = rbi + (size_t)((t0 + j - toff) & RM) * 512;
          pa[j] = FLD(rj + tid);
          pb[j] = FLD(rj + 256 + tid);
        }
      }

#pragma unroll
      for (int tt = 0; tt < CH; ++tt) {
        const int t = t0 + tt;

        // ---- stage x_t for layer A -> xstA[t&1]
        if (P > 0) {
          u16* xd = xstA[t & 1];
#pragma unroll
          for (int p = 0; p < 4; ++p) {
            xd[(srow + p) * 72 + scol]      = (u16)(pa[tt] >> (16 * p));
            xd[(srow + p) * 72 + scol + 16] = (u16)(pb[tt] >> (16 * p));
          }
        }

        lds_barrier();   // B1: xstA(t), hbA(t-1), hbB(t-1) visible

        // ---- probe issue (1 step before publish; latency hidden under compute)
        if (tt == PTT && tid == 0) {
          if (P > 0)  { f0 = FLD(fin + 0); f1 = FLD(fin + 1); f2 = FLD(fin + 2); f3 = FLD(fin + 3); }
          if (P < 31) { c0 = FLD(cnext + 0); c1 = FLD(cnext + 1); c2 = FLD(cnext + 2); c3 = FLD(cnext + 3); }
        }

        // ---- pair 31: projection of step t-1 (h63_{t-1} in hbB[(t+1)&1])
        if (P == 31 && t >= 257) do_proj(t - 1, hbB[(t + 1) & 1]);

        // ================= layer A =================
        f32x4 acc_rz[4], acc_in[2], acc_hn[2];
#pragma unroll
        for (int q = 0; q < 4; ++q) { float v = brzA[q]; f32x4 tv = {v,v,v,v}; acc_rz[q] = tv; }
#pragma unroll
        for (int q = 0; q < 2; ++q) { float v = binA[q]; f32x4 tv = {v,v,v,v}; acc_in[q] = tv;
                                      float w = bhnA[q]; f32x4 tw = {w,w,w,w}; acc_hn[q] = tw; }
        const u16* hsA = hbA[(t + 1) & 1];
#pragma unroll
        for (int kc = 0; kc < 2; ++kc) {
          short8 hA = *(const short8*)(hsA + (rt*16 + lo)*72 + kc*32 + hi*8);
          acc_rz[0] = __builtin_amdgcn_mfma_f32_16x16x32_bf16(hA, whA[0][kc], acc_rz[0], 0, 0, 0);
          acc_rz[1] = __builtin_amdgcn_mfma_f32_16x16x32_bf16(hA, whA[1][kc], acc_rz[1], 0, 0, 0);
          acc_rz[2] = __builtin_amdgcn_mfma_f32_16x16x32_bf16(hA, whA[2][kc], acc_rz[2], 0, 0, 0);
          acc_rz[3] = __builtin_amdgcn_mfma_f32_16x16x32_bf16(hA, whA[3][kc], acc_rz[3], 0, 0, 0);
          acc_hn[0] = __builtin_amdgcn_mfma_f32_16x16x32_bf16(hA, whA[4][kc], acc_hn[0], 0, 0, 0);
          acc_hn[1] = __builtin_amdgcn_mfma_f32_16x16x32_bf16(hA, whA[5][kc], acc_hn[1], 0, 0, 0);
        }
        short8 xfA[4] = {zf8, zf8, zf8, zf8};
        if (P > 0) {
          const u16* xs = xstA[t & 1];
#pragma unroll
          for (int kc = 0; kc < 2; ++kc)
            xfA[kc] = *(const short8*)(xs + (rt*16 + lo)*72 + kc*32 + hi*8);
        } else {
          int tx = (t < 256) ? t : ((t == 256) ? 0 : t - 257);
#pragma unroll
          for (int kc = 0; kc < 4; ++kc)
            xfA[kc] = ld8(ctx_, (brow * 256 + tx) * 128 + kc*32 + hi*8);
        }
        if (!(P == 0 && t == 256)) {
#pragma unroll
          for (int kc = 0; kc < 4; ++kc) {
            if (kc < NKCA) {
              acc_rz[0] = __builtin_amdgcn_mfma_f32_16x16x32_bf16(xfA[kc], wiA[0][kc], acc_rz[0], 0, 0, 0);
              acc_rz[1] = __builtin_amdgcn_mfma_f32_16x16x32_bf16(xfA[kc], wiA[1][kc], acc_rz[1], 0, 0, 0);
              acc_rz[2] = __builtin_amdgcn_mfma_f32_16x16x32_bf16(xfA[kc], wiA[2][kc], acc_rz[2], 0, 0, 0);
              acc_rz[3] = __builtin_amdgcn_mfma_f32_16x16x32_bf16(xfA[kc], wiA[3][kc], acc_rz[3], 0, 0, 0);
              acc_in[0] = __builtin_amdgcn_mfma_f32_16x16x32_bf16(xfA[kc], wiA[4][kc], acc_in[0], 0, 0, 0);
              acc_in[1] = __builtin_amdgcn_mfma_f32_16x16x32_bf16(xfA[kc], wiA[5][kc], acc_in[1], 0, 0, 0);
            }
          }
        }
        u16 hAb[2][4];
#pragma unroll
        for (int q = 0; q < 2; ++q)
#pragma unroll
          for (int p = 0; p < 4; ++p) {
            float r = sigm(acc_rz[q][p]);
            float z = sigm(acc_rz[2 + q][p]);
            float n = tanhf_(acc_in[q][p] + r * acc_hn[q][p]);
            float h = n + z * (hprevA[q][p] - n);
            h = fminf(1.f, fmaxf(-1.f, h));
            hprevA[q][p] = h;
            hAb[q][p] = f2bf(h);
          }

        // ---- probe publish (pre-B2 so next chunk's readers are ordered)
        if (tt == CH - 1 && tid == 0) {
          if (P > 0)  s_fin = imin(imin(f0, f1), imin(f2, f3));
          if (P < 31) s_cn  = imin(imin(c0, c1), imin(c2, c3));
        }

        {  // h_A -> hbA[t&1] (recurrence) and xstB (x for layer B)
          u16* hd = hbA[t & 1];
#pragma unroll
          for (int q = 0; q < 2; ++q)
#pragma unroll
            for (int p = 0; p < 4; ++p) {
              int ridx = (rt*16 + hi*4 + p) * 72 + cs*32 + q*16 + lo;
              hd[ridx] = hAb[q][p];
              xstB[ridx] = hAb[q][p];
            }
        }

        lds_barrier();   // B2: xstB(t) visible

        // ================= layer B =================
#pragma unroll
        for (int q = 0; q < 4; ++q) { float v = brzB[q]; f32x4 tv = {v,v,v,v}; acc_rz[q] = tv; }
#pragma unroll
        for (int q = 0; q < 2; ++q) { float v = binB[q]; f32x4 tv = {v,v,v,v}; acc_in[q] = tv;
                                      float w = bhnB[q]; f32x4 tw = {w,w,w,w}; acc_hn[q] = tw; }
        const u16* hsB = hbB[(t + 1) & 1];
#pragma unroll
        for (int kc = 0; kc < 2; ++kc) {
          short8 hB = *(const short8*)(hsB + (rt*16 + lo)*72 + kc*32 + hi*8);
          short8 xB = *(const short8*)(xstB + (rt*16 + lo)*72 + kc*32 + hi*8);
          acc_rz[0] = __builtin_amdgcn_mfma_f32_16x16x32_bf16(hB, whB[0][kc], acc_rz[0], 0, 0, 0);
          acc_rz[1] = __builtin_amdgcn_mfma_f32_16x16x32_bf16(hB, whB[1][kc], acc_rz[1], 0, 0, 0);
          acc_rz[2] = __builtin_amdgcn_mfma_f32_16x16x32_bf16(hB, whB[2][kc], acc_rz[2], 0, 0, 0);
          acc_rz[3] = __builtin_amdgcn_mfma_f32_16x16x32_bf16(hB, whB[3][kc], acc_rz[3], 0, 0, 0);
          acc_hn[0] = __builtin_amdgcn_mfma_f32_16x16x32_bf16(hB, whB[4][kc], acc_hn[0], 0, 0, 0);
          acc_hn[1] = __builtin_amdgcn_mfma_f32_16x16x32_bf16(hB, whB[5][kc], acc_hn[1], 0, 0, 0);
          acc_rz[0] = __builtin_amdgcn_mfma_f32_16x16x32_bf16(xB, wiB[0][kc], acc_rz[0], 0, 0, 0);
          acc_rz[1] = __builtin_amdgcn_mfma_f32_16x16x32_bf16(xB, wiB[1][kc], acc_rz[1], 0, 0, 0);
          acc_rz[2] = __builtin_amdgcn_mfma_f32_16x16x32_bf16(xB, wiB[2][kc], acc_rz[2], 0, 0, 0);
          acc_rz[3] = __builtin_amdgcn_mfma_f32_16x16x32_bf16(xB, wiB[3][kc], acc_rz[3], 0, 0, 0);
          acc_in[0] = __builtin_amdgcn_mfma_f32_16x16x32_bf16(xB, wiB[4][kc], acc_in[0], 0, 0, 0);
          acc_in[1] = __builtin_amdgcn_mfma_f32_16x16x32_bf16(xB, wiB[5][kc], acc_in[1], 0, 0, 0);
        }
        u16 hBb[2][4];
#pragma unroll
        for (int q = 0; q < 2; ++q)
#pragma unroll
          for (int p = 0; p < 4; ++p) {
            float r = sigm(acc_rz[q][p]);
            float z = sigm(acc_rz[2 + q][p]);
            float n = tanhf_(acc_in[q][p] + r * acc_hn[q][p]);
            float h = n + z * (hprevB[q][p] - n);
            h = fminf(1.f, fmaxf(-1.f, h));
            hprevB[q][p] = h;
            hBb[q][p] = f2bf(h);
          }
        {
          u16* hd = hbB[t & 1];
#pragma unroll
          for (int q = 0; q < 2; ++q)
#pragma unroll
            for (int p = 0; p < 4; ++p)
              hd[(rt*16 + hi*4 + p) * 72 + cs*32 + q*16 + lo] = hBb[q][p];
        }
        if (P < 31) {   // record h_B for the next pair (plane-split: full lines)
          u64 da = (u64)hBb[0][0] | ((u64)hBb[0][1] << 16) | ((u64)hBb[0][2] << 32) | ((u64)hBb[0][3] << 48);
          u64 db = (u64)hBb[1][0] | ((u64)hBb[1][1] << 16) | ((u64)hBb[1][2] << 32) | ((u64)hBb[1][3] << 48);
          u64* ro = rbo + (size_t)((t - toff) & RM) * 512;
          FST(ro + tid, da);
          FST(ro + 256 + tid, db);
        }
      }

      // ---- chunk end: per-wave drain + flag/credit (no __syncthreads)
      if (P < 31) {
        DRAIN0();                                   // wave's ring stores at MALL
        if (lane == 0) FST(fout + wid, ck + 1);
      }
      if (P > 0 && lane == 0) FST(cself + wid, ck + 1);  // wave's prime loads retired
    }
  };

  span(IC<CHE>{}, 0, 0, RE / CHE, false);        // encoder: ring in d_out
  load_phase(1);
  {
    int rcd = RW / CHD; if (rcd < 1) rcd = 1;
    span(IC<CHD>{}, 256, 256 / CHE, rcd, true);  // decoder: ring in workspace
  }

  // ---- epilogue: projection of the final step (t = 511)
  lds_barrier();
  if (P == 31) do_proj(511, hbB[1]);
}

extern "C" void kernel_launch(void* const* d_in, const int* in_sizes, int n_in,
                              void* d_out, int out_size, void* d_ws, size_t ws_size,
                              hipStream_t stream)
{
  char* ws = (char*)d_ws;
  int* pflag = (int*)ws;                    // 124 edges x 64B per-wave flag lines
  int* cflag = (int*)(ws + 8192);           // 128 x 64B per-wave credit lines
  u64* xbufW = (u64*)(ws + 16384);          // decoder-phase handoff ring

  const size_t per_slot = (size_t)31 * 4 * 4096;  // one ring step across all 31x4 edges
  size_t avail = (ws_size > 16384) ? ws_size - 16384 : 0;
  int RW = 1;
  for (int r = 128; r >= 1; r >>= 1)
    if ((size_t)r * per_slot <= avail) { RW = r; break; }
  // encoder-phase ring borrows d_out (dead until pair31's first projection)
  int RE = 1;
  for (int r = 16; r >= 1; r >>= 1)
    if ((size_t)r * per_slot <= (size_t)out_size) { RE = r; break; }

  hipMemsetAsync(ws, 0, 16384, stream);     // zero flags every launch

#define LAUNCH(CE, CD)                                                     \
  gru_pipeline<CE, CD><<<128, 256, 0, stream>>>(                           \
      d_in[0], d_in[1], d_in[2], d_in[3], d_in[4], d_in[5],                \
      d_in[6], d_in[7], d_in[8], d_in[9], d_in[10], d_in[11], d_in[12],    \
      d_out, pflag, cflag, xbufW, RW, RE)

  if (RE >= 4) {
    if      (RW >= 8) LAUNCH(4, 4);
    else if (RW >= 4) LAUNCH(4, 2);
    else              LAUNCH(4, 1);
  } else {
    LAUNCH(1, 1);
  }
#undef LAUNCH
  (void)in_sizes; (void)n_in;
}